// Round 1
// baseline (408.890 us; speedup 1.0000x reference)
//
#include <hip/hip_runtime.h>

// CASSI forward: out[b,l,m,n] = phi[m,n] * y2[b,m,2l+n]
//   y2[b,m,k] = sum_{l'} x[b,l',m,k-2l'] * phi[m,k-2l'],  0 <= k-2l' < N
// M=N=512, L=28, B=8, STRIDE=2, n_out = 512 + 2*27 = 566.
// One workgroup per (b,m) row: y2 (566 floats) lives in LDS, reused by all
// 28 output rows. Each x element is read exactly once; pure streaming kernel.

#define M_DIM 512
#define N_DIM 512
#define L_DIM 28
#define B_DIM 8
#define MN_DIM (M_DIM * N_DIM)
#define NOUT (N_DIM + 2 * (L_DIM - 1))  // 566

__global__ __launch_bounds__(256) void cassi_fwd_kernel(
    const float* __restrict__ x, const float* __restrict__ phi,
    float* __restrict__ out)
{
    __shared__ float sphi[N_DIM];
    __shared__ float sy2[NOUT + 2];  // +2 pad for aligned float2 stores

    const int tid = threadIdx.x;
    const int bm  = blockIdx.x;          // grid = B*M = 4096
    const int b   = bm >> 9;             // / 512
    const int m   = bm & (M_DIM - 1);

    // ---- Phase 1: stage phi[m,:] into LDS (256 threads x float2 = 512) ----
    {
        const float2* phi2 = (const float2*)(phi + (size_t)m * N_DIM);
        ((float2*)sphi)[tid] = phi2[tid];
    }
    __syncthreads();

    // ---- Phase 2: compute y2[k] for k in [0,566). ----
    // Thread t owns k-pair (2t, 2t+1)           [chunk0, k < 512]
    // Threads t<27 additionally own (512+2t, 513+2t) [chunk1, k >= 512]
    // chunk0 valid iff t >= l'; chunk1 valid iff t < l'. Complementary ->
    // exactly 28 aligned float2 loads per thread, fully coalesced.
    const float* xrow0 = x + (size_t)b * L_DIM * MN_DIM + (size_t)m * N_DIM;

    float2 acc0 = {0.f, 0.f};
    float2 acc1 = {0.f, 0.f};
#pragma unroll
    for (int l = 0; l < L_DIM; ++l) {
        const float* xr = xrow0 + (size_t)l * MN_DIM;
        if (tid >= l) {
            const int n = 2 * (tid - l);             // k = 2t, n = k - 2l
            float2 xv = *(const float2*)(xr + n);
            float2 pv = *(const float2*)(sphi + n);
            acc0.x += xv.x * pv.x;
            acc0.y += xv.y * pv.y;
        } else {                                     // tid < l  (=> tid <= 26)
            const int n = N_DIM - 2 * l + 2 * tid;   // k = 512+2t, n in [458,510]
            float2 xv = *(const float2*)(xr + n);
            float2 pv = *(const float2*)(sphi + n);
            acc1.x += xv.x * pv.x;
            acc1.y += xv.y * pv.y;
        }
    }
    *(float2*)(sy2 + 2 * tid) = acc0;
    if (tid < L_DIM - 1) {
        *(float2*)(sy2 + N_DIM + 2 * tid) = acc1;
    }
    __syncthreads();

    // ---- Phase 3: out[b,l,m,n] = sphi[n] * sy2[2l+n], float4 stores ----
    float* orow0 = out + (size_t)b * L_DIM * MN_DIM + (size_t)m * N_DIM;
    const float4* sphi4 = (const float4*)sphi;
#pragma unroll
    for (int it = 0; it < (L_DIM * (N_DIM / 4)) / 256; ++it) {  // 14 iters
        const int idx = tid + it * 256;
        const int l = idx >> 7;        // 128 float4 groups per row
        const int g = idx & 127;
        const int n = g * 4;
        // 2l+n is 8B-aligned (even) but not always 16B -> two float2 reads
        float2 ya = *(const float2*)(sy2 + 2 * l + n);
        float2 yb = *(const float2*)(sy2 + 2 * l + n + 2);
        float4 p = sphi4[g];
        float4 o;
        o.x = p.x * ya.x;
        o.y = p.y * ya.y;
        o.z = p.z * yb.x;
        o.w = p.w * yb.y;
        *(float4*)(orow0 + (size_t)l * MN_DIM + n) = o;
    }
}

extern "C" void kernel_launch(void* const* d_in, const int* in_sizes, int n_in,
                              void* d_out, int out_size, void* d_ws, size_t ws_size,
                              hipStream_t stream) {
    const float* x   = (const float*)d_in[0];
    const float* phi = (const float*)d_in[1];
    float* out       = (float*)d_out;
    cassi_fwd_kernel<<<dim3(B_DIM * M_DIM), dim3(256), 0, stream>>>(x, phi, out);
}

// Round 2
// 394.378 us; speedup vs baseline: 1.0368x; 1.0368x over previous
//
#include <hip/hip_runtime.h>

// CASSI forward: out[b,l,m,n] = phi[m,n] * y2[b,m,2l+n]
//   y2[b,m,k] = sum_{l'} x[b,l',m,k-2l'] * phi[m,k-2l'],  0 <= k-2l' < N
// M=N=512, L=28, B=8, STRIDE=2, n_out = 512 + 2*27 = 566.
// One workgroup per (b,m) row; y2 (566 floats) in LDS, reused by 28 out rows.
//
// R2: (a) phase-2 loads all 28 x float2s into a register array with
//     branchless addresses -> 28 loads in flight per wave (R1 had VGPR=32,
//     loads batched & serialized -> latency-bound at 31% HBM BW).
//     (b) phase-3 remapped to 8B-stride LDS reads (2-way aliasing = free;
//     R1's 16B stride was 8-way conflicted, 1.8M conflict cycles).
//     (c) nontemporal stores for out (write-once) to keep x resident in L3.

#define M_DIM 512
#define N_DIM 512
#define L_DIM 28
#define B_DIM 8
#define MN_DIM (M_DIM * N_DIM)
#define NOUT (N_DIM + 2 * (L_DIM - 1))  // 566

typedef float v2f __attribute__((ext_vector_type(2)));

__global__ __launch_bounds__(256) void cassi_fwd_kernel(
    const float* __restrict__ x, const float* __restrict__ phi,
    float* __restrict__ out)
{
    __shared__ float sphi[N_DIM];
    __shared__ float sy2[NOUT + 2];  // +2 pad so float2 stores stay in-bounds

    const int tid = threadIdx.x;
    const int bm  = blockIdx.x;          // grid = B*M = 4096
    const int b   = bm >> 9;             // / 512
    const int m   = bm & (M_DIM - 1);

    // ---- Phase 1: stage phi[m,:] into LDS (256 threads x float2) ----
    {
        const v2f* phi2 = (const v2f*)(phi + (size_t)m * N_DIM);
        ((v2f*)sphi)[tid] = phi2[tid];
    }
    __syncthreads();

    const v2f p2 = ((const v2f*)sphi)[tid];  // phi[m, 2*tid .. 2*tid+1]

    // ---- Phase 2: y2[k], thread t owns k=2t..2t+1 (and k=512+2t for t<27).
    // Branchless address per l: all 28 loads issued unconditionally so the
    // whole wave keeps 28 global loads in flight (MLP), then FMA from LDS.
    const float* xrow0 = x + (size_t)b * L_DIM * MN_DIM + (size_t)m * N_DIM;

    v2f xv[L_DIM];
#pragma unroll
    for (int l = 0; l < L_DIM; ++l) {
        // tid >= l: n = 2(tid-l)  (covers k=2t)
        // tid <  l: n = 512-2l+2tid (covers k=512+2t), only tid<=26 hits this
        const int n = (tid >= l) ? 2 * (tid - l) : (N_DIM - 2 * l + 2 * tid);
        xv[l] = *(const v2f*)(xrow0 + (size_t)l * MN_DIM + n);
    }

    v2f acc0 = {0.f, 0.f};
    v2f acc1 = {0.f, 0.f};
#pragma unroll
    for (int l = 0; l < L_DIM; ++l) {
        const int n = (tid >= l) ? 2 * (tid - l) : (N_DIM - 2 * l + 2 * tid);
        const v2f pv = *(const v2f*)(sphi + n);  // 8B stride -> conflict-free
        const v2f prod = xv[l] * pv;
        if (tid >= l) acc0 += prod;
        else          acc1 += prod;   // divergent only in wave 0
    }
    *(v2f*)(sy2 + 2 * tid) = acc0;
    if (tid < L_DIM - 1) {
        *(v2f*)(sy2 + N_DIM + 2 * tid) = acc1;
    }
    __syncthreads();

    // ---- Phase 3: out[b,l,m,2t..2t+1] = phi * y2[2l+2t..], loop over l.
    // LDS reads at 8B/lane stride (2-way aliasing, free). Nontemporal
    // float2 stores: out is write-once; don't evict x from L3.
    float* orow0 = out + (size_t)b * L_DIM * MN_DIM + (size_t)m * N_DIM;
#pragma unroll
    for (int l = 0; l < L_DIM; ++l) {
        const v2f y = *(const v2f*)(sy2 + 2 * l + 2 * tid);
        const v2f o = p2 * y;
        __builtin_nontemporal_store(o, (v2f*)(orow0 + (size_t)l * MN_DIM + 2 * tid));
    }
}

extern "C" void kernel_launch(void* const* d_in, const int* in_sizes, int n_in,
                              void* d_out, int out_size, void* d_ws, size_t ws_size,
                              hipStream_t stream) {
    const float* x   = (const float*)d_in[0];
    const float* phi = (const float*)d_in[1];
    float* out       = (float*)d_out;
    cassi_fwd_kernel<<<dim3(B_DIM * M_DIM), dim3(256), 0, stream>>>(x, phi, out);
}

// Round 3
// 389.861 us; speedup vs baseline: 1.0488x; 1.0116x over previous
//
#include <hip/hip_runtime.h>

// CASSI forward: out[b,l,m,n] = phi[m,n] * y2[b,m,2l+n]
//   y2[b,m,k] = sum_{l'} x[b,l',m,k-2l'] * phi[m,k-2l'],  0 <= k-2l' < N
// M=N=512, L=28, B=8, STRIDE=2, n_out = 566.
//
// R3 theory: R1/R2 both pinned at 2.5 TB/s with 8B/lane loads while
// fillBuffer (16B/lane) hits 6.6 TB/s -> per-VMEM-instruction throughput
// limit. This version makes ALL x loads aligned float4 (odd-l shift
// handled by __shfl_up from the neighbor lane's quad) and all stores
// float4. Thread t owns k-quad 4t..4t+3; threads t<14 also own tail quad
// 512+4t. Block = 2 m-rows (2x128 quad owners), grid = B*M/2 = 2048.

#define M_DIM 512
#define N_DIM 512
#define L_DIM 28
#define B_DIM 8
#define MN_DIM (M_DIM * N_DIM)
#define NT 14      // tail quads (k = 512+4t, t<14)
#define U_DIM 14   // l-pairs (l = 2u, 2u+1)

typedef float v2f __attribute__((ext_vector_type(2)));
typedef float v4f __attribute__((ext_vector_type(4)));

__global__ __launch_bounds__(256) void cassi_fwd_kernel(
    const float* __restrict__ x, const float* __restrict__ phi,
    float* __restrict__ out)
{
    __shared__ __align__(16) float sphi[2][N_DIM];   // per row-half
    __shared__ __align__(16) float sy2[2][576];      // k in [0,568), padded

    const int tid = threadIdx.x;
    const int r   = tid >> 7;        // row half 0/1
    const int t   = tid & 127;       // quad owner within row
    const int bm  = blockIdx.x;      // 0..2047
    const int b   = bm >> 8;
    const int m   = ((bm & 255) << 1) | r;

    const float* xrow = x + (size_t)b * L_DIM * MN_DIM + (size_t)m * N_DIM;

    // ---- Phase 1: stage phi row; keep own quad in regs for phase 3 ----
    v4f pq = *(const v4f*)(phi + (size_t)m * N_DIM + 4 * t);
    *(v4f*)&sphi[r][4 * t] = pq;
    __syncthreads();

    const float* sphif = &sphi[r][0];
    const bool lane0 = ((tid & 63) == 0);   // t == 0 or t == 64

    v4f acc  = {0.f, 0.f, 0.f, 0.f};
    v4f acct = {0.f, 0.f, 0.f, 0.f};

    // ---- Phase 2: for l-pair u, both l=2u (row re) and l=2u+1 (row ro)
    // read the ALIGNED quad at n = 4s, s = t-u. Even-l contributes the
    // quad directly (k = 4t+j). Odd-l needs z[4s-2..4s+1]: low half from
    // lane t-1's quad (shfl_up), high half from own quad's .xy.
#pragma unroll
    for (int u = 0; u < U_DIM; ++u) {
        const int s  = t - u;
        const int sc = s < 0 ? 0 : s;
        const float* re = xrow + (size_t)(2 * u) * MN_DIM;
        const float* ro = xrow + (size_t)(2 * u + 1) * MN_DIM;
        v4f xe = *(const v4f*)(re + 4 * sc);        // aligned 16B
        v4f xo = *(const v4f*)(ro + 4 * sc);        // aligned 16B
        v4f P  = *(const v4f*)(sphif + 4 * sc);     // phi[4s..4s+3]
        v4f ze = xe * P;
        v4f zo = xo * P;

        if (s >= 0) acc += ze;                      // l = 2u

        float lo0 = __shfl_up(zo.z, 1, 64);         // z[4s-2]
        float lo1 = __shfl_up(zo.w, 1, 64);         // z[4s-1]
        if (lane0 && s >= 1) {                      // wave boundary: t==64
            v2f xl = *(const v2f*)(ro + 4 * s - 2);
            v2f pl = *(const v2f*)(sphif + 4 * s - 2);
            lo0 = xl.x * pl.x;
            lo1 = xl.y * pl.y;
        }
        if (s >= 1) { acc.x += lo0;  acc.y += lo1; }   // l = 2u+1, j=0,1
        if (s >= 0) { acc.z += zo.x; acc.w += zo.y; }  // l = 2u+1, j=2,3

        // ---- tail quad k0 = 512+4t (threads t<14 only) ----
        if (t < NT) {
            if (u == t) {
                // only l = 2t+1 contributes: n = 510,511 -> j = 0,1
                v2f xl = *(const v2f*)(ro + 510);
                v2f pl = *(const v2f*)(sphif + 510);
                acct.x += xl.x * pl.x;
                acct.y += xl.y * pl.y;
            } else if (u > t) {
                const int n0 = 512 + 4 * t - 4 * u;  // in [460,508], aligned
                v4f xte = *(const v4f*)(re + n0);
                v4f Pt  = *(const v4f*)(sphif + n0);
                acct += xte * Pt;                    // l = 2u
                // l = 2u+1: j=0,1 at n0-2; j=2,3 at n0
                v2f xa = *(const v2f*)(ro + n0 - 2);
                v2f pa = *(const v2f*)(sphif + n0 - 2);
                v2f xb = *(const v2f*)(ro + n0);
                acct.x += xa.x * pa.x;
                acct.y += xa.y * pa.y;
                acct.z += xb.x * Pt.x;
                acct.w += xb.y * Pt.y;
            }
        }
    }

    *(v4f*)&sy2[r][4 * t] = acc;
    if (t < NT) *(v4f*)&sy2[r][512 + 4 * t] = acct;
    __syncthreads();

    // ---- Phase 3: out[b,l,m,4t..4t+3] = pq * y2[2l+4t..], float4 NT stores
    float* orow = out + (size_t)b * L_DIM * MN_DIM + (size_t)m * N_DIM;
    const float* sy = &sy2[r][0];
#pragma unroll
    for (int l = 0; l < L_DIM; ++l) {
        v2f ya = *(const v2f*)(sy + 2 * l + 4 * t);      // 8B-aligned
        v2f yb = *(const v2f*)(sy + 2 * l + 4 * t + 2);
        v4f o;
        o.x = pq.x * ya.x;
        o.y = pq.y * ya.y;
        o.z = pq.z * yb.x;
        o.w = pq.w * yb.y;
        __builtin_nontemporal_store(o, (v4f*)(orow + (size_t)l * MN_DIM + 4 * t));
    }
}

extern "C" void kernel_launch(void* const* d_in, const int* in_sizes, int n_in,
                              void* d_out, int out_size, void* d_ws, size_t ws_size,
                              hipStream_t stream) {
    const float* x   = (const float*)d_in[0];
    const float* phi = (const float*)d_in[1];
    float* out       = (float*)d_out;
    cassi_fwd_kernel<<<dim3(B_DIM * M_DIM / 2), dim3(256), 0, stream>>>(x, phi, out);
}